// Round 1
// baseline (1950.046 us; speedup 1.0000x reference)
//
#include <hip/hip_runtime.h>

#define SEQ 2048
#define DIM 1024

// ---------------------------------------------------------------------------
// NT GEMM: C[m][n] = alpha * sum_k A[m*K+k] * B[n*K+k]  (+ bias[n] if bias)
// A:[M,K] row-major, B:[N,K] row-major (both K-contiguous -> dot products).
// 64x64 tile, BK=16, 256 threads, 4x4 micro-tile/thread.
// ---------------------------------------------------------------------------
__global__ __launch_bounds__(256)
void gemm_nt(const float* __restrict__ A, const float* __restrict__ B,
             const float* __restrict__ bias, float* __restrict__ C,
             int M, int N, int K, float alpha,
             long sA, long sB, long sC)
{
    A += (long)blockIdx.z * sA;
    B += (long)blockIdx.z * sB;
    C += (long)blockIdx.z * sC;

    // +4 pad keeps ds_read_b128 16B-aligned (row stride 68*4=272 bytes)
    __shared__ float As[16][68];
    __shared__ float Bs[16][68];

    const int tid = threadIdx.x;
    const int m0 = blockIdx.x * 64;
    const int n0 = blockIdx.y * 64;

    // staging load map: thread t -> row t/4 of tile, 4 consecutive k
    const int lr = tid >> 2;          // 0..63
    const int lc = (tid & 3) << 2;    // 0,4,8,12
    // compute map: 16x16 thread grid, 4x4 outputs each
    const int tm = (tid >> 4) << 2;   // 0..60
    const int tn = (tid & 15) << 2;   // 0..60

    float acc[4][4] = {};

    const float* Ap = A + (long)(m0 + lr) * K + lc;
    const float* Bp = B + (long)(n0 + lr) * K + lc;

    for (int k0 = 0; k0 < K; k0 += 16) {
        float4 av = *(const float4*)(Ap + k0);
        float4 bv = *(const float4*)(Bp + k0);
        __syncthreads();
        As[lc + 0][lr] = av.x; As[lc + 1][lr] = av.y;
        As[lc + 2][lr] = av.z; As[lc + 3][lr] = av.w;
        Bs[lc + 0][lr] = bv.x; Bs[lc + 1][lr] = bv.y;
        Bs[lc + 2][lr] = bv.z; Bs[lc + 3][lr] = bv.w;
        __syncthreads();
#pragma unroll
        for (int kk = 0; kk < 16; ++kk) {
            float4 a = *(const float4*)&As[kk][tm];   // 16-lane broadcast
            float4 b = *(const float4*)&Bs[kk][tn];   // <=2-way bank alias
            acc[0][0] += a.x*b.x; acc[0][1] += a.x*b.y; acc[0][2] += a.x*b.z; acc[0][3] += a.x*b.w;
            acc[1][0] += a.y*b.x; acc[1][1] += a.y*b.y; acc[1][2] += a.y*b.z; acc[1][3] += a.y*b.w;
            acc[2][0] += a.z*b.x; acc[2][1] += a.z*b.y; acc[2][2] += a.z*b.z; acc[2][3] += a.z*b.w;
            acc[3][0] += a.w*b.x; acc[3][1] += a.w*b.y; acc[3][2] += a.w*b.z; acc[3][3] += a.w*b.w;
        }
    }

    float4 bb = make_float4(0.f, 0.f, 0.f, 0.f);
    if (bias) bb = *(const float4*)(bias + n0 + tn);
#pragma unroll
    for (int i = 0; i < 4; ++i) {
        float4 o;
        o.x = alpha * acc[i][0] + bb.x;
        o.y = alpha * acc[i][1] + bb.y;
        o.z = alpha * acc[i][2] + bb.z;
        o.w = alpha * acc[i][3] + bb.w;
        *(float4*)(C + (long)(m0 + tm + i) * N + n0 + tn) = o;
    }
}

// ---------------------------------------------------------------------------
// NN GEMM: C[m][n] = sum_k A[m*K+k] * B[k*N+n]   (P @ V)
// ---------------------------------------------------------------------------
__global__ __launch_bounds__(256)
void gemm_nn(const float* __restrict__ A, const float* __restrict__ B,
             float* __restrict__ C, int M, int N, int K,
             long sA, long sB, long sC)
{
    A += (long)blockIdx.z * sA;
    B += (long)blockIdx.z * sB;
    C += (long)blockIdx.z * sC;

    __shared__ float As[16][68];
    __shared__ float Bs[16][68];

    const int tid = threadIdx.x;
    const int m0 = blockIdx.x * 64;
    const int n0 = blockIdx.y * 64;

    const int lr = tid >> 2;          // A: row of tile
    const int lc = (tid & 3) << 2;    // A: 4 consecutive k
    const int kr = tid >> 4;          // B: k row 0..15
    const int nc = (tid & 15) << 2;   // B: 4 consecutive n
    const int tm = (tid >> 4) << 2;
    const int tn = (tid & 15) << 2;

    float acc[4][4] = {};

    const float* Ap = A + (long)(m0 + lr) * K + lc;
    const float* Bp = B + (long)kr * N + n0 + nc;

    for (int k0 = 0; k0 < K; k0 += 16) {
        float4 av = *(const float4*)(Ap + k0);
        float4 bv = *(const float4*)(Bp + (long)k0 * N);
        __syncthreads();
        As[lc + 0][lr] = av.x; As[lc + 1][lr] = av.y;
        As[lc + 2][lr] = av.z; As[lc + 3][lr] = av.w;
        *(float4*)&Bs[kr][nc] = bv;
        __syncthreads();
#pragma unroll
        for (int kk = 0; kk < 16; ++kk) {
            float4 a = *(const float4*)&As[kk][tm];
            float4 b = *(const float4*)&Bs[kk][tn];
            acc[0][0] += a.x*b.x; acc[0][1] += a.x*b.y; acc[0][2] += a.x*b.z; acc[0][3] += a.x*b.w;
            acc[1][0] += a.y*b.x; acc[1][1] += a.y*b.y; acc[1][2] += a.y*b.z; acc[1][3] += a.y*b.w;
            acc[2][0] += a.z*b.x; acc[2][1] += a.z*b.y; acc[2][2] += a.z*b.z; acc[2][3] += a.z*b.w;
            acc[3][0] += a.w*b.x; acc[3][1] += a.w*b.y; acc[3][2] += a.w*b.z; acc[3][3] += a.w*b.w;
        }
    }

#pragma unroll
    for (int i = 0; i < 4; ++i) {
        float4 o;
        o.x = acc[i][0]; o.y = acc[i][1]; o.z = acc[i][2]; o.w = acc[i][3];
        *(float4*)(C + (long)(m0 + tm + i) * N + n0 + tn) = o;
    }
}

// ---------------------------------------------------------------------------
// Row softmax over rows of length SEQ(2048). One 256-thread block per row.
// ---------------------------------------------------------------------------
__global__ __launch_bounds__(256)
void softmax_rows(float* __restrict__ S)
{
    float* row = S + (long)blockIdx.x * SEQ;
    const int tid  = threadIdx.x;
    const int wid  = tid >> 6;
    const int lane = tid & 63;

    float4 a = *(const float4*)(row + 4 * tid);
    float4 b = *(const float4*)(row + 1024 + 4 * tid);

    float m = fmaxf(fmaxf(fmaxf(a.x, a.y), fmaxf(a.z, a.w)),
                    fmaxf(fmaxf(b.x, b.y), fmaxf(b.z, b.w)));
    for (int off = 32; off > 0; off >>= 1)
        m = fmaxf(m, __shfl_down(m, off));

    __shared__ float red[4];
    __shared__ float bc[2];
    if (lane == 0) red[wid] = m;
    __syncthreads();
    if (tid == 0) bc[0] = fmaxf(fmaxf(red[0], red[1]), fmaxf(red[2], red[3]));
    __syncthreads();
    m = bc[0];

    a.x = __expf(a.x - m); a.y = __expf(a.y - m);
    a.z = __expf(a.z - m); a.w = __expf(a.w - m);
    b.x = __expf(b.x - m); b.y = __expf(b.y - m);
    b.z = __expf(b.z - m); b.w = __expf(b.w - m);

    float s = a.x + a.y + a.z + a.w + b.x + b.y + b.z + b.w;
    for (int off = 32; off > 0; off >>= 1)
        s += __shfl_down(s, off);
    if (lane == 0) red[wid] = s;
    __syncthreads();
    if (tid == 0) bc[1] = red[0] + red[1] + red[2] + red[3];
    __syncthreads();
    const float inv = 1.0f / bc[1];

    a.x *= inv; a.y *= inv; a.z *= inv; a.w *= inv;
    b.x *= inv; b.y *= inv; b.z *= inv; b.w *= inv;
    *(float4*)(row + 4 * tid) = a;
    *(float4*)(row + 1024 + 4 * tid) = b;
}

// ---------------------------------------------------------------------------
extern "C" void kernel_launch(void* const* d_in, const int* in_sizes, int n_in,
                              void* d_out, int out_size, void* d_ws, size_t ws_size,
                              hipStream_t stream)
{
    const float* x  = (const float*)d_in[0];
    const float* Wq = (const float*)d_in[1];
    const float* bq = (const float*)d_in[2];
    const float* Wk = (const float*)d_in[3];
    const float* bk = (const float*)d_in[4];
    const float* Wv = (const float*)d_in[5];
    const float* bv = (const float*)d_in[6];
    float* out = (float*)d_out;

    const long NTOK = 4L * SEQ;          // 8192 tokens
    const long PROJ = NTOK * DIM;        // q/k/v elements (32 MB each)
    const long SMAT = (long)SEQ * SEQ;   // per-batch score matrix (16 MB)
    const float scale = 0.03125f;        // 1/sqrt(1024)

    dim3 blk(256);

    if (ws_size >= (size_t)(3 * PROJ + 4 * SMAT) * sizeof(float)) {
        // Full layout: q,k,v for all batches + all 4 score matrices (160 MB)
        float* q = (float*)d_ws;
        float* k = q + PROJ;
        float* v = k + PROJ;
        float* S = v + PROJ;

        dim3 gp(NTOK / 64, DIM / 64, 1);
        gemm_nt<<<gp, blk, 0, stream>>>(x, Wq, bq, q, (int)NTOK, DIM, DIM, 1.0f, 0, 0, 0);
        gemm_nt<<<gp, blk, 0, stream>>>(x, Wk, bk, k, (int)NTOK, DIM, DIM, 1.0f, 0, 0, 0);
        gemm_nt<<<gp, blk, 0, stream>>>(x, Wv, bv, v, (int)NTOK, DIM, DIM, 1.0f, 0, 0, 0);

        dim3 gs(SEQ / 64, SEQ / 64, 4);
        gemm_nt<<<gs, blk, 0, stream>>>(q, k, nullptr, S, SEQ, SEQ, DIM, scale,
                                        (long)SEQ * DIM, (long)SEQ * DIM, SMAT);
        softmax_rows<<<4 * SEQ, blk, 0, stream>>>(S);

        dim3 go(SEQ / 64, DIM / 64, 4);
        gemm_nn<<<go, blk, 0, stream>>>(S, v, out, SEQ, DIM, SEQ,
                                        SMAT, (long)SEQ * DIM, (long)SEQ * DIM);
    } else {
        // Per-batch fallback: needs (3*SEQ*DIM + SEQ*SEQ)*4 = 40 MB
        float* q = (float*)d_ws;
        float* k = q + (long)SEQ * DIM;
        float* v = k + (long)SEQ * DIM;
        float* S = v + (long)SEQ * DIM;
        for (int b = 0; b < 4; ++b) {
            const float* xb = x + (long)b * SEQ * DIM;
            float* ob = out + (long)b * SEQ * DIM;
            dim3 gp(SEQ / 64, DIM / 64, 1);
            gemm_nt<<<gp, blk, 0, stream>>>(xb, Wq, bq, q, SEQ, DIM, DIM, 1.0f, 0, 0, 0);
            gemm_nt<<<gp, blk, 0, stream>>>(xb, Wk, bk, k, SEQ, DIM, DIM, 1.0f, 0, 0, 0);
            gemm_nt<<<gp, blk, 0, stream>>>(xb, Wv, bv, v, SEQ, DIM, DIM, 1.0f, 0, 0, 0);
            dim3 gs(SEQ / 64, SEQ / 64, 1);
            gemm_nt<<<gs, blk, 0, stream>>>(q, k, nullptr, S, SEQ, SEQ, DIM, scale, 0, 0, 0);
            softmax_rows<<<SEQ, blk, 0, stream>>>(S);
            dim3 go(SEQ / 64, DIM / 64, 1);
            gemm_nn<<<go, blk, 0, stream>>>(S, v, ob, SEQ, DIM, SEQ, 0, 0, 0);
        }
    }
}

// Round 2
// 311.872 us; speedup vs baseline: 6.2527x; 6.2527x over previous
//
#include <hip/hip_runtime.h>

#define SEQ  2048
#define DIM  1024
#define NTOK 8192   // 4*SEQ
#define NQKV 3072

#define BM 128
#define BN 128
#define BK 32

typedef __attribute__((ext_vector_type(8))) __bf16 bf16x8;
typedef __attribute__((ext_vector_type(4))) float  f32x4;

__device__ __forceinline__ unsigned short f2bf(float f) {
    unsigned int u = __float_as_uint(f);
    u += 0x7fffu + ((u >> 16) & 1u);          // round-to-nearest-even
    return (unsigned short)(u >> 16);
}

__device__ __forceinline__ void load_lds_128(const unsigned short* g, unsigned short* l) {
    __builtin_amdgcn_global_load_lds(
        (const __attribute__((address_space(1))) void*)g,
        (__attribute__((address_space(3))) void*)l, 16, 0, 0);
}

// ---------------------------------------------------------------------------
// NT GEMM, bf16 MFMA 16x16x32, 128x128 tile, BK=32, 256 thr (4 waves, 2x2).
// C[m][n] = sum_k A[m][k]*B[n][k]; A,B bf16 K-contiguous.
// MODE 0: C bf16, + bias picked from b0/b1/b2 by col>>10 (fused QKV).
// MODE 1: C fp32, * alpha.
// ---------------------------------------------------------------------------
template <int MODE>
__global__ __launch_bounds__(256)
void gemm_bt(const unsigned short* __restrict__ A, const unsigned short* __restrict__ B,
             void* __restrict__ Cv,
             const float* __restrict__ b0, const float* __restrict__ b1,
             const float* __restrict__ b2,
             int K, int lda, int ldb, int ldc,
             long sA, long sB, long sC, float alpha)
{
    __shared__ unsigned short As[BM * BK];
    __shared__ unsigned short Bs[BN * BK];

    const int tid  = threadIdx.x;
    const int wave = tid >> 6;
    const int lane = tid & 63;
    const int quad = lane >> 4;
    const int l15  = lane & 15;

    const int m0 = blockIdx.x * BM;
    const int n0 = blockIdx.y * BN;
    A += (long)blockIdx.z * sA;
    B += (long)blockIdx.z * sB;

    const int wm = (wave >> 1) * 64;
    const int wn = (wave & 1) * 64;

    f32x4 acc[4][4] = {};

    // staging: 16B chunk id; LDS layout forced contiguous (wave base + lane*16)
    const int ch = wave * 64 + lane;           // 0..255
    const int kc = (ch & 3) << 3;              // k elem offset 0/8/16/24
    const int rw = ch >> 2;                    // tile row 0..63
    const unsigned short* Ag0 = A + (long)(m0 + rw) * lda + kc;
    const unsigned short* Ag1 = A + (long)(m0 + 64 + rw) * lda + kc;
    const unsigned short* Bg0 = B + (long)(n0 + rw) * ldb + kc;
    const unsigned short* Bg1 = B + (long)(n0 + 64 + rw) * ldb + kc;
    unsigned short* Al0 = As + ch * 8;
    unsigned short* Al1 = As + (ch + 256) * 8;
    unsigned short* Bl0 = Bs + ch * 8;
    unsigned short* Bl1 = Bs + (ch + 256) * 8;

    const unsigned short* Afr = As + (wm + l15) * BK + quad * 8;
    const unsigned short* Bfr = Bs + (wn + l15) * BK + quad * 8;

    for (int k0 = 0; k0 < K; k0 += BK) {
        load_lds_128(Ag0 + k0, Al0);
        load_lds_128(Ag1 + k0, Al1);
        load_lds_128(Bg0 + k0, Bl0);
        load_lds_128(Bg1 + k0, Bl1);
        __syncthreads();                       // vmcnt(0) drain + barrier
        bf16x8 af[4], bf[4];
#pragma unroll
        for (int i = 0; i < 4; ++i) af[i] = *(const bf16x8*)(Afr + i * 16 * BK);
#pragma unroll
        for (int i = 0; i < 4; ++i) bf[i] = *(const bf16x8*)(Bfr + i * 16 * BK);
#pragma unroll
        for (int i = 0; i < 4; ++i)
#pragma unroll
            for (int j = 0; j < 4; ++j)
                acc[i][j] = __builtin_amdgcn_mfma_f32_16x16x32_bf16(af[i], bf[j], acc[i][j], 0, 0, 0);
        __syncthreads();                       // all reads done before next stage
    }

    // C/D layout: col = lane&15, row = quad*4 + reg  [m89/m91 verified]
    const int orow = m0 + wm + quad * 4;
    const int ocol = n0 + wn + l15;

    if (MODE == 0) {
        unsigned short* C16 = (unsigned short*)Cv;
#pragma unroll
        for (int j = 0; j < 4; ++j) {
            const int col = ocol + j * 16;
            const int seg = col >> 10;         // block n-range stays in one segment
            const float* bp = (seg == 0) ? b0 : ((seg == 1) ? b1 : b2);
            const float bias = bp[col & 1023];
#pragma unroll
            for (int i = 0; i < 4; ++i)
#pragma unroll
                for (int r = 0; r < 4; ++r)
                    C16[(long)(orow + i * 16 + r) * ldc + col] = f2bf(acc[i][j][r] + bias);
        }
    } else {
        float* C = (float*)Cv + (long)blockIdx.z * sC;
#pragma unroll
        for (int j = 0; j < 4; ++j) {
            const int col = ocol + j * 16;
#pragma unroll
            for (int i = 0; i < 4; ++i)
#pragma unroll
                for (int r = 0; r < 4; ++r)
                    C[(long)(orow + i * 16 + r) * ldc + col] = acc[i][j][r] * alpha;
        }
    }
}

// ---------------------------------------------------------------------------
// fp32 -> bf16 elementwise (n4 = n/4 float4 groups)
// ---------------------------------------------------------------------------
__global__ __launch_bounds__(256)
void cvt_f32_bf16(const float* __restrict__ src, unsigned short* __restrict__ dst, int n4)
{
    int i = blockIdx.x * 256 + threadIdx.x;
    if (i < n4) {
        float4 f = ((const float4*)src)[i];
        ushort4 u;
        u.x = f2bf(f.x); u.y = f2bf(f.y); u.z = f2bf(f.z); u.w = f2bf(f.w);
        ((ushort4*)dst)[i] = u;
    }
}

// ---------------------------------------------------------------------------
// Transpose V columns of qkv [8192 x 3072] (cols 2048..3071) into
// vt[b][d][m] (bf16, [4][1024][2048]), 64x64 LDS tiles.
// ---------------------------------------------------------------------------
__global__ __launch_bounds__(256)
void transpose_v(const unsigned short* __restrict__ qkv, unsigned short* __restrict__ vt)
{
    __shared__ unsigned short t[64][66];
    const int b  = blockIdx.z;
    const int m0 = blockIdx.x * 64;
    const int d0 = blockIdx.y * 64;
    const int r  = threadIdx.x >> 5;           // 0..7
    const int c2 = (threadIdx.x & 31) * 2;     // 0..62 even

#pragma unroll
    for (int j = 0; j < 64; j += 8) {
        const int m = j + r;
        unsigned int val = *(const unsigned int*)
            (qkv + (long)(b * SEQ + m0 + m) * NQKV + 2048 + d0 + c2);
        t[m][c2]     = (unsigned short)val;
        t[m][c2 + 1] = (unsigned short)(val >> 16);
    }
    __syncthreads();
#pragma unroll
    for (int j = 0; j < 64; j += 8) {
        const int d = j + r;
        unsigned int lo = t[c2][d];
        unsigned int hi = t[c2 + 1][d];
        *(unsigned int*)(vt + ((long)b * DIM + d0 + d) * SEQ + m0 + c2) = lo | (hi << 16);
    }
}

// ---------------------------------------------------------------------------
// Row softmax: fp32 S row (2048) -> bf16 P row. One 256-thr block per row.
// ---------------------------------------------------------------------------
__global__ __launch_bounds__(256)
void softmax_bf16(const float* __restrict__ S, unsigned short* __restrict__ P)
{
    const long roff = (long)blockIdx.x * SEQ;
    const float* row = S + roff;
    const int tid  = threadIdx.x;
    const int wid  = tid >> 6;
    const int lane = tid & 63;

    float4 a = ((const float4*)row)[tid];
    float4 b = ((const float4*)row)[tid + 256];

    float m = fmaxf(fmaxf(fmaxf(a.x, a.y), fmaxf(a.z, a.w)),
                    fmaxf(fmaxf(b.x, b.y), fmaxf(b.z, b.w)));
    for (int off = 32; off > 0; off >>= 1)
        m = fmaxf(m, __shfl_down(m, off));

    __shared__ float red[4];
    __shared__ float bc[2];
    if (lane == 0) red[wid] = m;
    __syncthreads();
    if (tid == 0) bc[0] = fmaxf(fmaxf(red[0], red[1]), fmaxf(red[2], red[3]));
    __syncthreads();
    m = bc[0];

    a.x = __expf(a.x - m); a.y = __expf(a.y - m);
    a.z = __expf(a.z - m); a.w = __expf(a.w - m);
    b.x = __expf(b.x - m); b.y = __expf(b.y - m);
    b.z = __expf(b.z - m); b.w = __expf(b.w - m);

    float s = a.x + a.y + a.z + a.w + b.x + b.y + b.z + b.w;
    for (int off = 32; off > 0; off >>= 1)
        s += __shfl_down(s, off);
    if (lane == 0) red[wid] = s;
    __syncthreads();
    if (tid == 0) bc[1] = red[0] + red[1] + red[2] + red[3];
    __syncthreads();
    const float inv = 1.0f / bc[1];

    unsigned short* prow = P + roff;
    ushort4 ua, ub;
    ua.x = f2bf(a.x * inv); ua.y = f2bf(a.y * inv);
    ua.z = f2bf(a.z * inv); ua.w = f2bf(a.w * inv);
    ub.x = f2bf(b.x * inv); ub.y = f2bf(b.y * inv);
    ub.z = f2bf(b.z * inv); ub.w = f2bf(b.w * inv);
    ((ushort4*)prow)[tid]       = ua;
    ((ushort4*)prow)[tid + 256] = ub;
}

// ---------------------------------------------------------------------------
extern "C" void kernel_launch(void* const* d_in, const int* in_sizes, int n_in,
                              void* d_out, int out_size, void* d_ws, size_t ws_size,
                              hipStream_t stream)
{
    const float* x  = (const float*)d_in[0];
    const float* Wq = (const float*)d_in[1];
    const float* bq = (const float*)d_in[2];
    const float* Wk = (const float*)d_in[3];
    const float* bk = (const float*)d_in[4];
    const float* Wv = (const float*)d_in[5];
    const float* bv = (const float*)d_in[6];
    float* out = (float*)d_out;

    // Workspace layout (ws_size >= 167.8MB proven in R1; need 160MB):
    //  [0,64MB):    S fp32 [4][2048][2048]  (aliases xb@0 +16MB Wb -- dead by GEMM2)
    //  [64,112MB):  qkv bf16 [8192][3072]
    //  [112,128MB): vt  bf16 [4][1024][2048]
    //  [128,160MB): P   bf16 [4][2048][2048]
    char* ws = (char*)d_ws;
    float*          Smat = (float*)ws;
    unsigned short* xb   = (unsigned short*)ws;
    unsigned short* Wb   = (unsigned short*)(ws + 16u * 1024 * 1024);
    unsigned short* qkv  = (unsigned short*)(ws + 64u * 1024 * 1024);
    unsigned short* vt   = (unsigned short*)(ws + 112u * 1024 * 1024);
    unsigned short* P    = (unsigned short*)(ws + 128u * 1024 * 1024);

    const float scale = 0.03125f;   // 1/sqrt(1024)
    dim3 blk(256);

    // 1) convert inputs to bf16
    cvt_f32_bf16<<<(NTOK * DIM / 4 + 255) / 256, blk, 0, stream>>>(x, xb, NTOK * DIM / 4);
    cvt_f32_bf16<<<(DIM * DIM / 4 + 255) / 256, blk, 0, stream>>>(Wq, Wb,                 DIM * DIM / 4);
    cvt_f32_bf16<<<(DIM * DIM / 4 + 255) / 256, blk, 0, stream>>>(Wk, Wb + DIM * DIM,     DIM * DIM / 4);
    cvt_f32_bf16<<<(DIM * DIM / 4 + 255) / 256, blk, 0, stream>>>(Wv, Wb + 2 * DIM * DIM, DIM * DIM / 4);

    // 2) fused QKV projection: qkv[8192,3072] = xb . Wb^T + bias (bf16 out)
    {
        dim3 g(NTOK / BM, NQKV / BN, 1);
        gemm_bt<0><<<g, blk, 0, stream>>>(xb, Wb, qkv, bq, bk, bv,
                                          DIM, DIM, DIM, NQKV, 0, 0, 0, 1.0f);
    }

    // 3) vt[b][d][m] = v[b][m][d]
    {
        dim3 g(SEQ / 64, DIM / 64, 4);
        transpose_v<<<g, blk, 0, stream>>>(qkv, vt);
    }

    // 4) S[b] = q[b] . k[b]^T * scale  (fp32 out)
    {
        dim3 g(SEQ / BM, SEQ / BN, 4);
        gemm_bt<1><<<g, blk, 0, stream>>>(qkv, qkv + 1024, Smat,
                                          nullptr, nullptr, nullptr,
                                          DIM, NQKV, NQKV, SEQ,
                                          (long)SEQ * NQKV, (long)SEQ * NQKV,
                                          (long)SEQ * SEQ, scale);
    }

    // 5) P = softmax(S) rows, bf16
    softmax_bf16<<<4 * SEQ, blk, 0, stream>>>(Smat, P);

    // 6) out[b] = P[b] . vt[b]^T  (fp32 out)
    {
        dim3 g(SEQ / BM, DIM / BN, 4);
        gemm_bt<1><<<g, blk, 0, stream>>>(P, vt, out,
                                          nullptr, nullptr, nullptr,
                                          SEQ, SEQ, SEQ, DIM,
                                          (long)SEQ * SEQ, (long)DIM * SEQ,
                                          (long)SEQ * DIM, 1.0f);
    }
}

// Round 3
// 301.429 us; speedup vs baseline: 6.4693x; 1.0346x over previous
//
#include <hip/hip_runtime.h>

#define SEQ  2048
#define DIM  1024
#define NTOK 8192   // 4*SEQ
#define NQKV 3072
#define BK   32

typedef __attribute__((ext_vector_type(8)))  __bf16 bf16x8;
typedef __attribute__((ext_vector_type(16))) float  f32x16;

__device__ __forceinline__ unsigned short f2bf(float f) {
    unsigned int u = __float_as_uint(f);
    u += 0x7fffu + ((u >> 16) & 1u);          // round-to-nearest-even
    return (unsigned short)(u >> 16);
}

__device__ __forceinline__ void load_lds_128(const unsigned short* g, unsigned short* l) {
    __builtin_amdgcn_global_load_lds(
        (const __attribute__((address_space(1))) void*)g,
        (__attribute__((address_space(3))) void*)l, 16, 0, 0);
}

// ---------------------------------------------------------------------------
// NT GEMM, bf16 MFMA 32x32x16, 128x128 block, BK=32, 4 waves (2x2 of 64x64).
// C[m][n] = sum_k A[m][k]*B[n][k].
// LDS k-chunk rotation: row r, slot c holds global chunk (c - (r>>1)) & 3.
// MODE 0: fused QKV epilogue -- n<2048: bf16 qkv + bias(b0/b1 by col>>10);
//         n>=2048: transposed write to vt[d][m] + bias b2 (packed ushort4).
// MODE 1: fp32 C, * alpha.
// ---------------------------------------------------------------------------
template <int MODE>
__global__ __launch_bounds__(256)
void gemm_bt(const unsigned short* __restrict__ A, const unsigned short* __restrict__ B,
             void* __restrict__ Cv,
             const float* __restrict__ b0, const float* __restrict__ b1,
             const float* __restrict__ b2, unsigned short* __restrict__ vt,
             int K, int lda, int ldb, int ldc,
             long sA, long sB, long sC, float alpha)
{
    __shared__ unsigned short As[128 * BK];
    __shared__ unsigned short Bs[128 * BK];

    const int tid  = threadIdx.x;
    const int wave = tid >> 6;
    const int lane = tid & 63;
    const int l31  = lane & 31;
    const int half = lane >> 5;

    const int m0 = blockIdx.x * 128;
    const int n0 = blockIdx.y * 128;
    A += (long)blockIdx.z * sA;
    B += (long)blockIdx.z * sB;

    const int wm = (wave >> 1) * 64;
    const int wn = (wave & 1) * 64;

    f32x16 acc[2][2] = {};

    // ---- staging map (lane-constant): tile row tid>>2, slot tid&3 ----
    const int srow = tid >> 2;
    const int slot = tid & 3;
    const int g    = (slot - (srow >> 1)) & 3;       // global chunk for this slot
    const unsigned short* Ag0 = A + (long)(m0 + srow) * lda + g * 8;
    const unsigned short* Ag1 = A + (long)(m0 + 64 + srow) * lda + g * 8;
    const unsigned short* Bg0 = B + (long)(n0 + srow) * ldb + g * 8;
    const unsigned short* Bg1 = B + (long)(n0 + 64 + srow) * ldb + g * 8;
    unsigned short* Al0 = As + tid * 8;
    unsigned short* Al1 = As + (tid + 256) * 8;
    unsigned short* Bl0 = Bs + tid * 8;
    unsigned short* Bl1 = Bs + (tid + 256) * 8;

    // ---- fragment pointers (lane-constant): un-rotate the k-chunk ----
    // A[m=lane&31][k=(lane>>5)*8+j]; gw = chunk index h*2+half at row rr
    const unsigned short* Af[2][2];
    const unsigned short* Bf[2][2];
#pragma unroll
    for (int i = 0; i < 2; ++i)
#pragma unroll
        for (int h = 0; h < 2; ++h) {
            const int gw  = h * 2 + half;
            const int rrA = wm + i * 32 + l31;
            const int rrB = wn + i * 32 + l31;
            Af[i][h] = As + rrA * BK + ((gw + (rrA >> 1)) & 3) * 8;
            Bf[i][h] = Bs + rrB * BK + ((gw + (rrB >> 1)) & 3) * 8;
        }

    for (int k0 = 0; k0 < K; k0 += BK) {
        load_lds_128(Ag0 + k0, Al0);
        load_lds_128(Ag1 + k0, Al1);
        load_lds_128(Bg0 + k0, Bl0);
        load_lds_128(Bg1 + k0, Bl1);
        __syncthreads();                       // vmcnt(0) drain + barrier
        bf16x8 a[2][2], b[2][2];
#pragma unroll
        for (int i = 0; i < 2; ++i)
#pragma unroll
            for (int h = 0; h < 2; ++h) {
                a[i][h] = *(const bf16x8*)Af[i][h];
                b[i][h] = *(const bf16x8*)Bf[i][h];
            }
#pragma unroll
        for (int h = 0; h < 2; ++h)
#pragma unroll
            for (int i = 0; i < 2; ++i)
#pragma unroll
                for (int j = 0; j < 2; ++j)
                    acc[i][j] = __builtin_amdgcn_mfma_f32_32x32x16_bf16(
                        a[i][h], b[j][h], acc[i][j], 0, 0, 0);
        __syncthreads();
    }

    // C/D: col = lane&31, row = (reg&3) + 8*(reg>>2) + 4*(lane>>5)  [m74/m101]
    if (MODE == 0) {
        if (n0 >= 2048) {
            // V part -> vt[b][d][m], packed 4-row stores
#pragma unroll
            for (int j = 0; j < 2; ++j) {
                const int d = n0 - 2048 + wn + j * 32 + l31;
                const float bias = b2[d];
#pragma unroll
                for (int i = 0; i < 2; ++i) {
                    const int mbase = m0 + wm + i * 32 + 4 * half;
#pragma unroll
                    for (int rq = 0; rq < 4; ++rq) {
                        const int rowi = mbase + 8 * rq;
                        const int bb = rowi >> 11;
                        const int mm = rowi & 2047;
                        ushort4 u;
                        u.x = f2bf(acc[i][j][rq * 4 + 0] + bias);
                        u.y = f2bf(acc[i][j][rq * 4 + 1] + bias);
                        u.z = f2bf(acc[i][j][rq * 4 + 2] + bias);
                        u.w = f2bf(acc[i][j][rq * 4 + 3] + bias);
                        *(ushort4*)(vt + ((long)bb * DIM + d) * SEQ + mm) = u;
                    }
                }
            }
        } else {
            unsigned short* C16 = (unsigned short*)Cv;
#pragma unroll
            for (int j = 0; j < 2; ++j) {
                const int col = n0 + wn + j * 32 + l31;
                const float* bp = (col >> 10) ? b1 : b0;
                const float bias = bp[col & 1023];
#pragma unroll
                for (int i = 0; i < 2; ++i)
#pragma unroll
                    for (int r = 0; r < 16; ++r) {
                        const int rowi = m0 + wm + i * 32 + (r & 3) + 8 * (r >> 2) + 4 * half;
                        C16[(long)rowi * ldc + col] = f2bf(acc[i][j][r] + bias);
                    }
            }
        }
    } else {
        float* C = (float*)Cv + (long)blockIdx.z * sC;
#pragma unroll
        for (int j = 0; j < 2; ++j) {
            const int col = n0 + wn + j * 32 + l31;
#pragma unroll
            for (int i = 0; i < 2; ++i)
#pragma unroll
                for (int r = 0; r < 16; ++r) {
                    const int rowi = m0 + wm + i * 32 + (r & 3) + 8 * (r >> 2) + 4 * half;
                    C[(long)rowi * ldc + col] = acc[i][j][r] * alpha;
                }
        }
    }
}

// ---------------------------------------------------------------------------
__global__ __launch_bounds__(256)
void cvt_x(const float* __restrict__ src, unsigned short* __restrict__ dst, int n4)
{
    int i = blockIdx.x * 256 + threadIdx.x;
    if (i < n4) {
        float4 f = ((const float4*)src)[i];
        ushort4 u;
        u.x = f2bf(f.x); u.y = f2bf(f.y); u.z = f2bf(f.z); u.w = f2bf(f.w);
        ((ushort4*)dst)[i] = u;
    }
}

__global__ __launch_bounds__(256)
void cvt_w3(const float* __restrict__ Wq, const float* __restrict__ Wk,
            const float* __restrict__ Wv, unsigned short* __restrict__ dst)
{
    const int sel = blockIdx.y;
    const float* src = (sel == 0) ? Wq : ((sel == 1) ? Wk : Wv);
    const int i = blockIdx.x * 256 + threadIdx.x;     // DIM*DIM/4 elems
    float4 f = ((const float4*)src)[i];
    ushort4 u;
    u.x = f2bf(f.x); u.y = f2bf(f.y); u.z = f2bf(f.z); u.w = f2bf(f.w);
    ((ushort4*)(dst + (long)sel * DIM * DIM))[i] = u;
}

// ---------------------------------------------------------------------------
// Row softmax: fp32 S row (2048) -> bf16 P row. One 256-thr block per row.
// ---------------------------------------------------------------------------
__global__ __launch_bounds__(256)
void softmax_bf16(const float* __restrict__ S, unsigned short* __restrict__ P)
{
    const long roff = (long)blockIdx.x * SEQ;
    const float* row = S + roff;
    const int tid  = threadIdx.x;
    const int wid  = tid >> 6;
    const int lane = tid & 63;

    float4 a = ((const float4*)row)[tid];
    float4 b = ((const float4*)row)[tid + 256];

    float m = fmaxf(fmaxf(fmaxf(a.x, a.y), fmaxf(a.z, a.w)),
                    fmaxf(fmaxf(b.x, b.y), fmaxf(b.z, b.w)));
    for (int off = 32; off > 0; off >>= 1)
        m = fmaxf(m, __shfl_down(m, off));

    __shared__ float red[4];
    __shared__ float bc[2];
    if (lane == 0) red[wid] = m;
    __syncthreads();
    if (tid == 0) bc[0] = fmaxf(fmaxf(red[0], red[1]), fmaxf(red[2], red[3]));
    __syncthreads();
    m = bc[0];

    a.x = __expf(a.x - m); a.y = __expf(a.y - m);
    a.z = __expf(a.z - m); a.w = __expf(a.w - m);
    b.x = __expf(b.x - m); b.y = __expf(b.y - m);
    b.z = __expf(b.z - m); b.w = __expf(b.w - m);

    float s = a.x + a.y + a.z + a.w + b.x + b.y + b.z + b.w;
    for (int off = 32; off > 0; off >>= 1)
        s += __shfl_down(s, off);
    if (lane == 0) red[wid] = s;
    __syncthreads();
    if (tid == 0) bc[1] = red[0] + red[1] + red[2] + red[3];
    __syncthreads();
    const float inv = 1.0f / bc[1];

    unsigned short* prow = P + roff;
    ushort4 ua, ub;
    ua.x = f2bf(a.x * inv); ua.y = f2bf(a.y * inv);
    ua.z = f2bf(a.z * inv); ua.w = f2bf(a.w * inv);
    ub.x = f2bf(b.x * inv); ub.y = f2bf(b.y * inv);
    ub.z = f2bf(b.z * inv); ub.w = f2bf(b.w * inv);
    ((ushort4*)prow)[tid]       = ua;
    ((ushort4*)prow)[tid + 256] = ub;
}

// ---------------------------------------------------------------------------
extern "C" void kernel_launch(void* const* d_in, const int* in_sizes, int n_in,
                              void* d_out, int out_size, void* d_ws, size_t ws_size,
                              hipStream_t stream)
{
    const float* x  = (const float*)d_in[0];
    const float* Wq = (const float*)d_in[1];
    const float* bq = (const float*)d_in[2];
    const float* Wk = (const float*)d_in[3];
    const float* bk = (const float*)d_in[4];
    const float* Wv = (const float*)d_in[5];
    const float* bv = (const float*)d_in[6];
    float* out = (float*)d_out;

    // Workspace (>=167.8MB proven R1; need 160MB):
    //  [0,64MB):    S fp32 [4][2048][2048]   (aliases xb@0 + Wb@16MB, dead by GEMM2)
    //  [64,112MB):  qkv bf16 [8192][3072]    (V cols never written; vt instead)
    //  [112,128MB): vt  bf16 [4][1024][2048]
    //  [128,160MB): P   bf16 [4][2048][2048]
    char* ws = (char*)d_ws;
    float*          Smat = (float*)ws;
    unsigned short* xb   = (unsigned short*)ws;
    unsigned short* Wb   = (unsigned short*)(ws + 16u * 1024 * 1024);
    unsigned short* qkv  = (unsigned short*)(ws + 64u * 1024 * 1024);
    unsigned short* vt   = (unsigned short*)(ws + 112u * 1024 * 1024);
    unsigned short* P    = (unsigned short*)(ws + 128u * 1024 * 1024);

    const float scale = 0.03125f;   // 1/sqrt(1024)
    dim3 blk(256);

    // 1) converts
    cvt_x<<<NTOK * DIM / 4 / 256, blk, 0, stream>>>(x, xb, NTOK * DIM / 4);
    cvt_w3<<<dim3(DIM * DIM / 4 / 256, 3), blk, 0, stream>>>(Wq, Wk, Wv, Wb);

    // 2) fused QKV projection (V transposed into vt in-epilogue)
    gemm_bt<0><<<dim3(NTOK / 128, NQKV / 128), blk, 0, stream>>>(
        xb, Wb, qkv, bq, bk, bv, vt,
        DIM, DIM, DIM, NQKV, 0, 0, 0, 1.0f);

    // 3) S[b] = q[b] . k[b]^T * scale (fp32)
    gemm_bt<1><<<dim3(SEQ / 128, SEQ / 128, 4), blk, 0, stream>>>(
        qkv, qkv + 1024, Smat, nullptr, nullptr, nullptr, nullptr,
        DIM, NQKV, NQKV, SEQ,
        (long)SEQ * NQKV, (long)SEQ * NQKV, (long)SEQ * SEQ, scale);

    // 4) P = softmax(S), bf16
    softmax_bf16<<<4 * SEQ, blk, 0, stream>>>(Smat, P);

    // 5) out[b] = P[b] . vt[b]^T (fp32)
    gemm_bt<1><<<dim3(SEQ / 128, DIM / 128, 4), blk, 0, stream>>>(
        P, vt, out, nullptr, nullptr, nullptr, nullptr,
        SEQ, SEQ, SEQ, DIM,
        (long)SEQ * SEQ, (long)DIM * SEQ, (long)SEQ * DIM, 1.0f);
}

// Round 4
// 261.579 us; speedup vs baseline: 7.4549x; 1.1523x over previous
//
#include <hip/hip_runtime.h>

#define SEQ  2048
#define DIM  1024
#define NTOK 8192   // 4*SEQ
#define NQKV 3072
#define BK   64

typedef __attribute__((ext_vector_type(8)))  __bf16 bf16x8;
typedef __attribute__((ext_vector_type(16))) float  f32x16;

__device__ __forceinline__ unsigned short f2bf(float f) {
    unsigned int u = __float_as_uint(f);
    u += 0x7fffu + ((u >> 16) & 1u);          // round-to-nearest-even
    return (unsigned short)(u >> 16);
}

__device__ __forceinline__ float bfu2f(unsigned int lo16) {
    return __uint_as_float(lo16 << 16);
}

__device__ __forceinline__ void load_lds_128(const unsigned short* g, unsigned short* l) {
    __builtin_amdgcn_global_load_lds(
        (const __attribute__((address_space(1))) void*)g,
        (__attribute__((address_space(3))) void*)l, 16, 0, 0);
}

// ---------------------------------------------------------------------------
// NT GEMM, bf16 MFMA 32x32x16, 128x128 block, BK=64, 4 waves (2x2 of 64x64).
// LDS rows of 64 elems = 8 chunks of 16B; slot c of row r holds global
// chunk (c - r) & 7 (rotate-by-row -> ds_read_b128 at 8-wrap minimum).
// MODE 0: fused QKV epilogue (q,k bf16 + bias; v transposed into vt + bias)
// MODE 1: fp32 C = acc * inv_rs[row]   (normalized P.V output)
// MODE 2: bf16 C = exp(acc * alpha)    (unnormalized softmax numerator)
// ---------------------------------------------------------------------------
template <int MODE>
__global__ __launch_bounds__(256)
void gemm_bt(const unsigned short* __restrict__ A, const unsigned short* __restrict__ B,
             void* __restrict__ Cv,
             const float* __restrict__ b0, const float* __restrict__ b1,
             const float* __restrict__ b2, unsigned short* __restrict__ vt,
             const float* __restrict__ inv_rs,
             int K, int lda, int ldb, int ldc,
             long sA, long sB, long sC, float alpha)
{
    __shared__ unsigned short As[128 * BK];   // 16 KB
    __shared__ unsigned short Bs[128 * BK];   // 16 KB

    const int tid  = threadIdx.x;
    const int wave = tid >> 6;
    const int lane = tid & 63;
    const int l31  = lane & 31;
    const int half = lane >> 5;

    const int m0 = blockIdx.x * 128;
    const int n0 = blockIdx.y * 128;
    const int z  = blockIdx.z;
    A += (long)z * sA;
    B += (long)z * sB;

    const int wm = (wave >> 1) * 64;
    const int wn = (wave & 1) * 64;

    f32x16 acc[2][2] = {};

    // ---- staging map: chunk ch = tid + 256p -> row ch>>3, slot ch&7 ----
    // row r_p = (tid>>3) + 32p; slot c = tid&7; global chunk g = (c - r) & 7
    // (p-invariant since 32p % 8 == 0)
    const int r0 = tid >> 3;
    const int g  = ((tid & 7) - r0) & 7;
    const unsigned short* Ag = A + (long)(m0 + r0) * lda + g * 8;
    const unsigned short* Bg = B + (long)(n0 + r0) * ldb + g * 8;
    unsigned short* Al = As + tid * 8;
    unsigned short* Bl = Bs + tid * 8;

    // ---- fragment LDS offsets (lane-constant), un-rotated ----
    // A[m=l31 (+i*32)][k = h*16 + half*8 + j] -> chunk gw = h*2 + half
    const unsigned short* Af[2][4];
    const unsigned short* Bf[2][4];
#pragma unroll
    for (int i = 0; i < 2; ++i) {
        const int rrA = wm + i * 32 + l31;
        const int rrB = wn + i * 32 + l31;
#pragma unroll
        for (int h = 0; h < 4; ++h) {
            const int gw = h * 2 + half;
            Af[i][h] = As + rrA * BK + (((gw + rrA) & 7) << 3);
            Bf[i][h] = Bs + rrB * BK + (((gw + rrB) & 7) << 3);
        }
    }

    for (int k0 = 0; k0 < K; k0 += BK) {
#pragma unroll
        for (int p = 0; p < 4; ++p) {
            load_lds_128(Ag + k0 + (long)(32 * p) * lda, Al + 2048 * p);
            load_lds_128(Bg + k0 + (long)(32 * p) * ldb, Bl + 2048 * p);
        }
        __syncthreads();                       // vmcnt(0) drain + barrier
        bf16x8 a[2][4], b[2][4];
#pragma unroll
        for (int i = 0; i < 2; ++i)
#pragma unroll
            for (int h = 0; h < 4; ++h) {
                a[i][h] = *(const bf16x8*)Af[i][h];
                b[i][h] = *(const bf16x8*)Bf[i][h];
            }
#pragma unroll
        for (int h = 0; h < 4; ++h)
#pragma unroll
            for (int i = 0; i < 2; ++i)
#pragma unroll
                for (int j = 0; j < 2; ++j)
                    acc[i][j] = __builtin_amdgcn_mfma_f32_32x32x16_bf16(
                        a[i][h], b[j][h], acc[i][j], 0, 0, 0);
        __syncthreads();
    }

    // C/D: col = lane&31, row = (reg&3) + 8*(reg>>2) + 4*(lane>>5)  [m74/m101]
    if (MODE == 0) {
        if (n0 >= 2048) {
            // V columns -> vt[b][d][m] (+bias), packed 4-m ushort4 stores
#pragma unroll
            for (int j = 0; j < 2; ++j) {
                const int d = n0 - 2048 + wn + j * 32 + l31;
                const float bias = b2[d];
#pragma unroll
                for (int i = 0; i < 2; ++i) {
                    const int mbase = m0 + wm + i * 32 + 4 * half;
#pragma unroll
                    for (int rq = 0; rq < 4; ++rq) {
                        const int rowi = mbase + 8 * rq;
                        const int bb = rowi >> 11;
                        const int mm = rowi & 2047;
                        ushort4 u;
                        u.x = f2bf(acc[i][j][rq * 4 + 0] + bias);
                        u.y = f2bf(acc[i][j][rq * 4 + 1] + bias);
                        u.z = f2bf(acc[i][j][rq * 4 + 2] + bias);
                        u.w = f2bf(acc[i][j][rq * 4 + 3] + bias);
                        *(ushort4*)(vt + ((long)bb * DIM + d) * SEQ + mm) = u;
                    }
                }
            }
        } else {
            unsigned short* C16 = (unsigned short*)Cv;
#pragma unroll
            for (int j = 0; j < 2; ++j) {
                const int col = n0 + wn + j * 32 + l31;
                const float* bp = (col >> 10) ? b1 : b0;
                const float bias = bp[col & 1023];
#pragma unroll
                for (int i = 0; i < 2; ++i)
#pragma unroll
                    for (int r = 0; r < 16; ++r) {
                        const int rowi = m0 + wm + i * 32 + (r & 3) + 8 * (r >> 2) + 4 * half;
                        C16[(long)rowi * ldc + col] = f2bf(acc[i][j][r] + bias);
                    }
            }
        }
    } else if (MODE == 1) {
        float* C = (float*)Cv + (long)z * sC;
        const float* ir = inv_rs + (long)z * SEQ;
#pragma unroll
        for (int i = 0; i < 2; ++i) {
            const int rbase = m0 + wm + i * 32 + 4 * half;
#pragma unroll
            for (int rq = 0; rq < 4; ++rq) {
                const float4 inv4 = *(const float4*)(ir + rbase + 8 * rq);
#pragma unroll
                for (int j = 0; j < 2; ++j) {
                    const int col = n0 + wn + j * 32 + l31;
                    C[(long)(rbase + 8 * rq + 0) * ldc + col] = acc[i][j][rq * 4 + 0] * inv4.x;
                    C[(long)(rbase + 8 * rq + 1) * ldc + col] = acc[i][j][rq * 4 + 1] * inv4.y;
                    C[(long)(rbase + 8 * rq + 2) * ldc + col] = acc[i][j][rq * 4 + 2] * inv4.z;
                    C[(long)(rbase + 8 * rq + 3) * ldc + col] = acc[i][j][rq * 4 + 3] * inv4.w;
                }
            }
        }
    } else {  // MODE 2: P = exp(acc * alpha), bf16, unnormalized
        unsigned short* C16 = (unsigned short*)Cv + (long)z * sC;
#pragma unroll
        for (int j = 0; j < 2; ++j) {
            const int col = n0 + wn + j * 32 + l31;
#pragma unroll
            for (int i = 0; i < 2; ++i)
#pragma unroll
                for (int r = 0; r < 16; ++r) {
                    const int rowi = m0 + wm + i * 32 + (r & 3) + 8 * (r >> 2) + 4 * half;
                    C16[(long)rowi * ldc + col] = f2bf(__expf(acc[i][j][r] * alpha));
                }
        }
    }
}

// ---------------------------------------------------------------------------
__global__ __launch_bounds__(256)
void cvt_x(const float* __restrict__ src, unsigned short* __restrict__ dst, int n4)
{
    int i = blockIdx.x * 256 + threadIdx.x;
    if (i < n4) {
        float4 f = ((const float4*)src)[i];
        ushort4 u;
        u.x = f2bf(f.x); u.y = f2bf(f.y); u.z = f2bf(f.z); u.w = f2bf(f.w);
        ((ushort4*)dst)[i] = u;
    }
}

__global__ __launch_bounds__(256)
void cvt_w3(const float* __restrict__ Wq, const float* __restrict__ Wk,
            const float* __restrict__ Wv, unsigned short* __restrict__ dst)
{
    const int sel = blockIdx.y;
    const float* src = (sel == 0) ? Wq : ((sel == 1) ? Wk : Wv);
    const int i = blockIdx.x * 256 + threadIdx.x;
    float4 f = ((const float4*)src)[i];
    ushort4 u;
    u.x = f2bf(f.x); u.y = f2bf(f.y); u.z = f2bf(f.z); u.w = f2bf(f.w);
    ((ushort4*)(dst + (long)sel * DIM * DIM))[i] = u;
}

// ---------------------------------------------------------------------------
// inv_rs[row] = 1 / sum(P[row][:]) over 2048 bf16 values. 1 wave per row.
// ---------------------------------------------------------------------------
__global__ __launch_bounds__(256)
void rowsum_inv(const unsigned short* __restrict__ P, float* __restrict__ inv_rs)
{
    const int row  = blockIdx.x * 4 + (threadIdx.x >> 6);
    const int lane = threadIdx.x & 63;
    const unsigned short* pr = P + (long)row * SEQ;

    float s = 0.f;
#pragma unroll
    for (int it = 0; it < 4; ++it) {
        uint4 u = *(const uint4*)(pr + (it * 64 + lane) * 8);
        s += bfu2f(u.x & 0xffffu) + __uint_as_float(u.x & 0xffff0000u);
        s += bfu2f(u.y & 0xffffu) + __uint_as_float(u.y & 0xffff0000u);
        s += bfu2f(u.z & 0xffffu) + __uint_as_float(u.z & 0xffff0000u);
        s += bfu2f(u.w & 0xffffu) + __uint_as_float(u.w & 0xffff0000u);
    }
    for (int off = 32; off > 0; off >>= 1)
        s += __shfl_xor(s, off);
    if (lane == 0) inv_rs[row] = 1.0f / s;
}

// ---------------------------------------------------------------------------
extern "C" void kernel_launch(void* const* d_in, const int* in_sizes, int n_in,
                              void* d_out, int out_size, void* d_ws, size_t ws_size,
                              hipStream_t stream)
{
    const float* x  = (const float*)d_in[0];
    const float* Wq = (const float*)d_in[1];
    const float* bq = (const float*)d_in[2];
    const float* Wk = (const float*)d_in[3];
    const float* bk = (const float*)d_in[4];
    const float* Wv = (const float*)d_in[5];
    const float* bv = (const float*)d_in[6];
    float* out = (float*)d_out;

    // Workspace (>=167.8MB proven R1; need 160MB + 32KB):
    //  [0,16MB):    xb bf16 [8192][1024]
    //  [16,22MB):   Wb bf16 [3][1024][1024]
    //  [64,112MB):  qkv bf16 [8192][3072]  (V cols never written; vt instead)
    //  [112,128MB): vt  bf16 [4][1024][2048]
    //  [128,160MB): P   bf16 [4][2048][2048]  (unnormalized exp)
    //  [160MB,+32KB): inv_rs fp32 [8192]
    char* ws = (char*)d_ws;
    unsigned short* xb   = (unsigned short*)ws;
    unsigned short* Wb   = (unsigned short*)(ws + 16u * 1024 * 1024);
    unsigned short* qkv  = (unsigned short*)(ws + 64u * 1024 * 1024);
    unsigned short* vt   = (unsigned short*)(ws + 112u * 1024 * 1024);
    unsigned short* P    = (unsigned short*)(ws + 128u * 1024 * 1024);
    float*          irs  = (float*)(ws + 160u * 1024 * 1024);

    const float scale = 0.03125f;   // 1/sqrt(1024)
    dim3 blk(256);

    // 1) converts
    cvt_x<<<NTOK * DIM / 4 / 256, blk, 0, stream>>>(x, xb, NTOK * DIM / 4);
    cvt_w3<<<dim3(DIM * DIM / 4 / 256, 3), blk, 0, stream>>>(Wq, Wk, Wv, Wb);

    // 2) fused QKV projection (V transposed into vt in-epilogue)
    gemm_bt<0><<<dim3(NTOK / 128, NQKV / 128), blk, 0, stream>>>(
        xb, Wb, qkv, bq, bk, bv, vt, nullptr,
        DIM, DIM, DIM, NQKV, 0, 0, 0, 1.0f);

    // 3) P[b] = exp(q[b] . k[b]^T * scale)  (bf16, unnormalized)
    gemm_bt<2><<<dim3(SEQ / 128, SEQ / 128, 4), blk, 0, stream>>>(
        qkv, qkv + 1024, P, nullptr, nullptr, nullptr, nullptr, nullptr,
        DIM, NQKV, NQKV, SEQ,
        (long)SEQ * NQKV, (long)SEQ * NQKV, (long)SEQ * SEQ, scale);

    // 4) inv_rs = 1 / rowsum(P)
    rowsum_inv<<<NTOK / 4, blk, 0, stream>>>(P, irs);

    // 5) out[b] = (P[b] . vt[b]^T) * inv_rs   (fp32)
    gemm_bt<1><<<dim3(SEQ / 128, DIM / 128, 4), blk, 0, stream>>>(
        P, vt, out, nullptr, nullptr, nullptr, nullptr, irs,
        SEQ, SEQ, SEQ, DIM,
        (long)SEQ * SEQ, (long)DIM * SEQ, (long)SEQ * DIM, 1.0f);
}